// Round 8
// baseline (122.778 us; speedup 1.0000x reference)
//
#include <hip/hip_runtime.h>
#include <hip/hip_bf16.h>

#define HH 512
#define WW 640
#define HW (HH*WW)
#define PW 642                 // padded width  (+1 each side)
#define PH 514                 // padded height
#define PPB (PH*PW)            // 329,988 padded px per batch
#define NPPX (4*PPB)           // 1,319,952

typedef short short8  __attribute__((ext_vector_type(8)));
typedef short short4v __attribute__((ext_vector_type(4)));
typedef float f32x16  __attribute__((ext_vector_type(16)));
typedef float f32x4   __attribute__((ext_vector_type(4)));

__device__ inline short f2bf(float f) {
    __hip_bfloat16 h = __float2bfloat16(f);
    short s; __builtin_memcpy(&s, &h, 2);
    return s;
}

// ---- prep: fold BN into w1, bias as 10th tap row, transpose to MFMA layouts ----
__global__ void prep_weights(const float* __restrict__ w1, const float* __restrict__ b1,
                             const float* __restrict__ gamma, const float* __restrict__ beta,
                             const float* __restrict__ rmean, const float* __restrict__ rvar,
                             const float* __restrict__ w2,
                             short* __restrict__ ws_w1, short* __restrict__ ws_w2)
{
    int tid = blockIdx.x*blockDim.x + threadIdx.x;
    int stride = gridDim.x*blockDim.x;
    for (int i = tid; i < 4608; i += stride) {          // w1: [oc][c][t] -> [t][oc32][c16] * A_oc
        int oc = i / 144, rem = i - oc*144, c = rem / 9, t = rem - c*9;
        float a = gamma[oc] * rsqrtf(rvar[oc] + 1e-5f);
        ws_w1[t*512 + oc*16 + c] = f2bf(w1[i] * a);
    }
    for (int i = tid; i < 512; i += stride) {           // tap 9 = bias row (c==0 one-hot)
        int oc = i >> 4, c = i & 15;
        float a = gamma[oc] * rsqrtf(rvar[oc] + 1e-5f);
        float bias = beta[oc] + (b1[oc] - rmean[oc]) * a;
        ws_w1[9*512 + i] = (c == 0) ? f2bf(bias) : (short)0;
    }
    for (int i = tid; i < 4608; i += stride) {          // w2: [f][c][t] -> [t][f16][c32], f>=9 zero
        int t = i >> 9, f = (i >> 5) & 15, c = i & 31;
        float val = (f < 9) ? w2[(f*32 + c)*9 + t] : 0.f;
        ws_w2[i] = f2bf(val);
    }
}

// ---- prep_pad: img -> zero-padded NHWC bf16; depth -> replicate-padded fp32;
//      zero the h1-pad border ----
__global__ void prep_pad(const float* __restrict__ depth, const float* __restrict__ img,
                         short* __restrict__ img_pad, short* __restrict__ h1_pad,
                         float* __restrict__ depth_pad)
{
    int idx = blockIdx.x*256 + threadIdx.x;
    if (idx >= NPPX) return;
    int b = idx / PPB; int rem = idx - b*PPB;
    int py = rem / PW; int px = rem - py*PW;
    int cy = min(max(py - 1, 0), HH-1), cx = min(max(px - 1, 0), WW-1);
    depth_pad[idx] = depth[(size_t)b*HW + cy*WW + cx];
    bool interior = (py >= 1) && (py <= HH) && (px >= 1) && (px <= WW);
    if (interior) {
        const float* p = img + (size_t)b*16*HW + (py - 1)*WW + (px - 1);
        short8 v0, v1;
        #pragma unroll
        for (int c = 0; c < 8; ++c) v0[c] = f2bf(p[c*HW]);
        #pragma unroll
        for (int c = 0; c < 8; ++c) v1[c] = f2bf(p[(c+8)*HW]);
        *(short8*)&img_pad[(size_t)idx*16]     = v0;
        *(short8*)&img_pad[(size_t)idx*16 + 8] = v1;
    } else {
        short8 z = (short8)0;
        *(short8*)&img_pad[(size_t)idx*16]     = z;
        *(short8*)&img_pad[(size_t)idx*16 + 8] = z;
        #pragma unroll
        for (int q = 0; q < 4; ++q)
            *(short8*)&h1_pad[(size_t)idx*32 + q*8] = z;
    }
}

// ---- k1: conv1 (32x32x16 MFMA, 9 taps + bias tap), global->global, no LDS/barriers ----
__launch_bounds__(256, 4)
__global__ void k1_conv1(const short* __restrict__ img_pad,
                         const short* __restrict__ ws_w1,
                         short* __restrict__ h1_pad)
{
    // 2048 blocks = 8 XCDs x 256; one block = one image row (b, y)
    int nid = blockIdx.x;
    int oid = (nid & 7)*256 + (nid >> 3);
    int b = oid >> 9, y = oid & 511;

    const int tid = threadIdx.x, lane = tid & 63, wid = tid >> 6;
    const int l = lane & 31, cg = lane >> 5;

    short8 a1[10];
    #pragma unroll
    for (int t = 0; t < 10; ++t)
        a1[t] = *(const short8*)&ws_w1[t*512 + l*16 + cg*8];
    short8 bb = (short8)0;
    bb[0] = (cg == 0) ? (short)0x3F80 : (short)0;

    const short* ip = img_pad + (size_t)b*PPB*16;
    short*       hp = h1_pad  + (size_t)b*PPB*32;

    #pragma unroll
    for (int gi = 0; gi < 5; ++gi) {
        int col = (wid + 4*gi)*32 + l;                 // 0..639
        const short* b0 = ip + ((size_t)y*PW + col)*16 + cg*8;
        f32x16 acc;
        #pragma unroll
        for (int i = 0; i < 16; ++i) acc[i] = 0.f;
        acc = __builtin_amdgcn_mfma_f32_32x32x16_bf16(a1[9], bb, acc, 0, 0, 0);
        #pragma unroll
        for (int ty = 0; ty < 3; ++ty)
            #pragma unroll
            for (int tx = 0; tx < 3; ++tx)
                acc = __builtin_amdgcn_mfma_f32_32x32x16_bf16(
                        a1[ty*3 + tx],
                        *(const short8*)&b0[ty*(PW*16) + tx*16], acc, 0, 0, 0);

        size_t ho = ((size_t)(y + 1)*PW + (col + 1))*32;
        #pragma unroll
        for (int q = 0; q < 4; ++q) {                  // channels 8q + 4cg + 0..3
            short4v h;
            #pragma unroll
            for (int j = 0; j < 4; ++j)
                h[j] = f2bf(fmaxf(acc[q*4 + j], 0.f));
            *(short4v*)&hp[ho + 8*q + 4*cg] = h;
        }
    }
}

// ---- k2: conv2 (16x16x32 MFMA, sliding rows) + softmax + depth gather ----
__launch_bounds__(256, 4)
__global__ void k2_conv2(const short* __restrict__ h1_pad,
                         const float* __restrict__ depth_pad,
                         const short* __restrict__ ws_w2,
                         float* __restrict__ out)
{
    // 10240 blocks = 8 XCDs x 1280; tile 16 px wide x 8 rows; wave = 2 rows
    int nid = blockIdx.x;
    int oid = (nid & 7)*1280 + (nid >> 3);
    int b = oid / 2560; int rem = oid - b*2560;
    int ty = rem / 40, tx = rem - ty*40;
    const int gy0 = ty*8, gx0 = tx*16;

    const int tid = threadIdx.x, lane = tid & 63, wid = tid >> 6;
    const int fl = lane & 15, cg2 = lane >> 4;

    short8 a2[9];
    #pragma unroll
    for (int t = 0; t < 9; ++t)
        a2[t] = *(const short8*)&ws_w2[t*512 + fl*32 + cg2*8];

    const short* hp = h1_pad   + (size_t)b*PPB*32;
    const float* dp = depth_pad + (size_t)b*PPB;

    const int r0   = gy0 + 2*wid;       // first out row of this wave
    const int colh = gx0 + fl;

    short8 F[4][3];                     // h1 padded rows r0..r0+3, cols colh+dx
    #pragma unroll
    for (int i = 0; i < 4; ++i)
        #pragma unroll
        for (int dx = 0; dx < 3; ++dx)
            F[i][dx] = *(const short8*)&hp[((size_t)(r0 + i)*PW + colh + dx)*32 + cg2*8];

    f32x4 acc0, acc1;
    #pragma unroll
    for (int i = 0; i < 4; ++i) { acc0[i] = 0.f; acc1[i] = 0.f; }
    #pragma unroll
    for (int i = 0; i < 3; ++i)
        #pragma unroll
        for (int dx = 0; dx < 3; ++dx)
            acc0 = __builtin_amdgcn_mfma_f32_16x16x32_bf16(a2[i*3 + dx], F[i][dx], acc0, 0, 0, 0);
    #pragma unroll
    for (int i = 0; i < 3; ++i)
        #pragma unroll
        for (int dx = 0; dx < 3; ++dx)
            acc1 = __builtin_amdgcn_mfma_f32_16x16x32_bf16(a2[i*3 + dx], F[i + 1][dx], acc1, 0, 0, 0);

    #pragma unroll
    for (int rr = 0; rr < 2; ++rr) {
        f32x4 lg = rr ? acc1 : acc0;
        int oy = r0 + rr;
        float num = 0.f, den = 0.f;
        #pragma unroll
        for (int r = 0; r < 4; ++r) {
            int f = cg2*4 + r;                        // conv2 output channel
            if (f < 9) {
                float e = __expf(lg[r]);
                int fy = f/3, fx = f - fy*3;
                float d = dp[(size_t)(oy + fy)*PW + colh + fx];
                den += e; num += e * d;
            }
        }
        num += __shfl_xor(num, 16); den += __shfl_xor(den, 16);
        num += __shfl_xor(num, 32); den += __shfl_xor(den, 32);
        if (cg2 == 0)
            out[(size_t)b*HW + (size_t)oy*WW + colh] = num / den;
    }
}

// ================= fallback: R6 fused kernel (ws too small) =================
#define IMPLANEP (432*8 + 8)
#define H1PLANEP (360*8 + 8)

__launch_bounds__(256, 4)
__global__ void fastprop_fused(const float* __restrict__ depth,
                               const float* __restrict__ img,
                               const short* __restrict__ ws_w1,
                               const short* __restrict__ ws_w2,
                               float* __restrict__ out)
{
    __shared__ short s_img[2*IMPLANEP];
    __shared__ short s_h1 [4*H1PLANEP];
    __shared__ float s_depth[340];

    const int tid = threadIdx.x;
    int nid = blockIdx.x;
    int oid = (nid & 7)*640 + (nid >> 3);
    int bz = oid / 1280; int rem = oid - bz*1280;
    int by = rem / 20;   int bx = rem - by*20;
    const int gy0 = by*8, gx0 = bx*32;

    const float* imgb = img   + (size_t)bz*16*HW;
    const float* dpb  = depth + (size_t)bz*HW;
    const int lane = tid & 63;
    const int wid  = tid >> 6;

    const int oc = lane & 31, cg = lane >> 5;
    short8 a1[10];
    #pragma unroll
    for (int t = 0; t < 10; ++t)
        a1[t] = *(const short8*)&ws_w1[t*512 + oc*16 + cg*8];
    short8 bb = (short8)0;
    bb[0] = (cg == 0) ? (short)0x3F80 : (short)0;

    for (int g = tid; g < 864; g += 256) {
        int pixel = g >> 1, half = g & 1;
        int iy = pixel / 36, ix = pixel - iy*36;
        int gy = gy0 + iy - 2, gx = gx0 + ix - 2;
        bool v = ((unsigned)gy < HH) && ((unsigned)gx < WW);
        int cy = min(max(gy, 0), HH-1), cx = min(max(gx, 0), WW-1);
        const float* p = imgb + (size_t)(half*8)*HW + cy*WW + cx;
        float m = v ? 1.f : 0.f;
        short8 vv;
        #pragma unroll
        for (int c = 0; c < 8; ++c) vv[c] = f2bf(m * p[c*HW]);
        *(short8*)&s_img[half*IMPLANEP + pixel*8] = vv;
    }
    #pragma unroll
    for (int it = 0; it < 2; ++it) {
        int idx = tid + it*256;
        if (idx < 340) {
            int dty = idx / 34, dtx = idx - dty*34;
            int gy = min(max(gy0 + dty - 1, 0), HH-1);
            int gx = min(max(gx0 + dtx - 1, 0), WW-1);
            s_depth[idx] = dpb[gy*WW + gx];
        }
    }
    __syncthreads();

    {
        const int OFS1[9] = {0, 8, 16, 288, 296, 304, 576, 584, 592};
        const int px = lane & 31;
        #pragma unroll
        for (int gi = 0; gi < 3; ++gi) {
            int g    = wid + gi*4;
            int hp   = g*32 + px;
            int base = cg*IMPLANEP + hp*8;
            f32x16 acc;
            #pragma unroll
            for (int i = 0; i < 16; ++i) acc[i] = 0.f;
            acc = __builtin_amdgcn_mfma_f32_32x32x16_bf16(a1[9], bb, acc, 0, 0, 0);
            #pragma unroll
            for (int t = 0; t < 9; ++t)
                acc = __builtin_amdgcn_mfma_f32_32x32x16_bf16(
                         a1[t], *(const short8*)&s_img[base + OFS1[t]], acc, 0, 0, 0);
            if (hp < 360) {
                unsigned hy = (unsigned)hp / 36u;
                int hx = hp - (int)hy*36;
                int gy = gy0 + (int)hy - 1, gx = gx0 + hx - 1;
                bool inb = ((unsigned)gy < HH) && ((unsigned)gx < WW);
                #pragma unroll
                for (int q = 0; q < 4; ++q) {
                    short4v h;
                    #pragma unroll
                    for (int j = 0; j < 4; ++j) {
                        float hv = fmaxf(acc[q*4 + j], 0.f);
                        h[j] = inb ? f2bf(hv) : (short)0;
                    }
                    *(short4v*)&s_h1[q*H1PLANEP + hp*8 + 4*cg] = h;
                }
            }
        }
    }
    __syncthreads();

    {
        const int fl = lane & 15, cg2 = lane >> 4;
        short8 a2[9];
        #pragma unroll
        for (int t = 0; t < 9; ++t)
            a2[t] = *(const short8*)&ws_w2[t*512 + fl*32 + cg2*8];
        const int r0 = 2*wid;
        #pragma unroll
        for (int chh = 0; chh < 2; ++chh) {
            const int ox0 = chh*16;
            const int colbase = cg2*H1PLANEP + (ox0 + fl)*8;
            short8 F[4][3];
            #pragma unroll
            for (int i = 0; i < 4; ++i)
                #pragma unroll
                for (int dx = 0; dx < 3; ++dx)
                    F[i][dx] = *(const short8*)&s_h1[colbase + ((r0 + i)*36 + dx)*8];
            f32x4 acc0, acc1;
            #pragma unroll
            for (int i = 0; i < 4; ++i) { acc0[i] = 0.f; acc1[i] = 0.f; }
            #pragma unroll
            for (int i = 0; i < 3; ++i)
                #pragma unroll
                for (int dx = 0; dx < 3; ++dx)
                    acc0 = __builtin_amdgcn_mfma_f32_16x16x32_bf16(a2[i*3+dx], F[i][dx], acc0, 0, 0, 0);
            #pragma unroll
            for (int i = 0; i < 3; ++i)
                #pragma unroll
                for (int dx = 0; dx < 3; ++dx)
                    acc1 = __builtin_amdgcn_mfma_f32_16x16x32_bf16(a2[i*3+dx], F[i+1][dx], acc1, 0, 0, 0);
            #pragma unroll
            for (int rr = 0; rr < 2; ++rr) {
                f32x4 lg = rr ? acc1 : acc0;
                int oy = r0 + rr, ox = ox0 + fl;
                float num = 0.f, den = 0.f;
                #pragma unroll
                for (int r = 0; r < 4; ++r) {
                    int f = cg2*4 + r;
                    if (f < 9) {
                        float e = __expf(lg[r]);
                        int fy = f/3, fx = f - fy*3;
                        float d = s_depth[(oy + fy)*34 + (ox + fx)];
                        den += e; num += e * d;
                    }
                }
                num += __shfl_xor(num, 16); den += __shfl_xor(den, 16);
                num += __shfl_xor(num, 32); den += __shfl_xor(den, 32);
                if (cg2 == 0)
                    out[(size_t)bz*HW + (size_t)(gy0 + oy)*WW + (gx0 + ox)] = num / den;
            }
        }
    }
}

extern "C" void kernel_launch(void* const* d_in, const int* in_sizes, int n_in,
                              void* d_out, int out_size, void* d_ws, size_t ws_size,
                              hipStream_t stream) {
    const float* depth = (const float*)d_in[0];
    const float* img   = (const float*)d_in[1];
    const float* w1    = (const float*)d_in[2];
    const float* b1    = (const float*)d_in[3];
    const float* gamma = (const float*)d_in[4];
    const float* beta  = (const float*)d_in[5];
    const float* rmean = (const float*)d_in[6];
    const float* rvar  = (const float*)d_in[7];
    const float* w2    = (const float*)d_in[8];
    float* out = (float*)d_out;

    short* ws_w1 = (short*)d_ws;                         // 5120 shorts
    short* ws_w2 = ws_w1 + 5120;                         // 4608 shorts

    const size_t OFF_IMG   = 20480;
    const size_t SZ_IMG    = (size_t)NPPX*16*2;          // 42,238,464
    const size_t OFF_H1    = OFF_IMG + SZ_IMG;
    const size_t SZ_H1     = (size_t)NPPX*32*2;          // 84,476,928
    const size_t OFF_DEPTH = OFF_H1 + SZ_H1;
    const size_t SZ_DEPTH  = (size_t)NPPX*4;             //  5,279,808
    const size_t WS_NEEDED = OFF_DEPTH + SZ_DEPTH;       // 132,015,680

    prep_weights<<<16, 256, 0, stream>>>(w1, b1, gamma, beta, rmean, rvar, w2,
                                         ws_w1, ws_w2);

    if (ws_size >= WS_NEEDED) {
        short* img_pad   = (short*)((char*)d_ws + OFF_IMG);
        short* h1_pad    = (short*)((char*)d_ws + OFF_H1);
        float* depth_pad = (float*)((char*)d_ws + OFF_DEPTH);

        prep_pad<<<(NPPX + 255)/256, 256, 0, stream>>>(depth, img, img_pad, h1_pad, depth_pad);
        k1_conv1<<<2048, 256, 0, stream>>>(img_pad, ws_w1, h1_pad);
        k2_conv2<<<10240, 256, 0, stream>>>(h1_pad, depth_pad, ws_w2, out);
    } else {
        fastprop_fused<<<5120, 256, 0, stream>>>(depth, img, ws_w1, ws_w2, out);
    }
}

// Round 9
// 72.910 us; speedup vs baseline: 1.6840x; 1.6840x over previous
//
#include <hip/hip_runtime.h>
#include <hip/hip_bf16.h>

#define HH 512
#define WW 640
#define HW (HH*WW)
#define NT 512
#define IMPLANEP (432*8 + 8)    // img plane stride in shorts (36x12 pix, +16B pad)
#define H1PLANEP (360*8 + 8)    // h1 plane stride in shorts (36x10 pix, +16B pad)

typedef short short8  __attribute__((ext_vector_type(8)));
typedef short short4v __attribute__((ext_vector_type(4)));
typedef float f32x16  __attribute__((ext_vector_type(16)));
typedef float f32x4   __attribute__((ext_vector_type(4)));

__device__ inline short f2bf(float f) {
    __hip_bfloat16 h = __float2bfloat16(f);
    short s; __builtin_memcpy(&s, &h, 2);
    return s;
}

// ---- prep: fold BN into w1, bias as 10th tap row, transpose to MFMA layouts ----
__global__ void prep_weights(const float* __restrict__ w1, const float* __restrict__ b1,
                             const float* __restrict__ gamma, const float* __restrict__ beta,
                             const float* __restrict__ rmean, const float* __restrict__ rvar,
                             const float* __restrict__ w2,
                             short* __restrict__ ws_w1, short* __restrict__ ws_w2)
{
    int tid = blockIdx.x*blockDim.x + threadIdx.x;
    int stride = gridDim.x*blockDim.x;
    for (int i = tid; i < 4608; i += stride) {          // w1: [oc][c][t] -> [t][oc32][c16] * A_oc
        int oc = i / 144, rem = i - oc*144, c = rem / 9, t = rem - c*9;
        float a = gamma[oc] * rsqrtf(rvar[oc] + 1e-5f);
        ws_w1[t*512 + oc*16 + c] = f2bf(w1[i] * a);
    }
    for (int i = tid; i < 512; i += stride) {           // tap 9 = bias row (c==0 one-hot)
        int oc = i >> 4, c = i & 15;
        float a = gamma[oc] * rsqrtf(rvar[oc] + 1e-5f);
        float bias = beta[oc] + (b1[oc] - rmean[oc]) * a;
        ws_w1[9*512 + i] = (c == 0) ? f2bf(bias) : (short)0;
    }
    for (int i = tid; i < 4608; i += stride) {          // w2: [f][c][t] -> [t][f16][c32], f>=9 zero
        int t = i >> 9, f = (i >> 5) & 15, c = i & 31;
        float val = (f < 9) ? w2[(f*32 + c)*9 + t] : 0.f;
        ws_w2[i] = f2bf(val);
    }
}

// ---------------- main fused kernel: 512 thr (8 waves), 32x8 tile ----------------
__launch_bounds__(NT, 4)
__global__ void fastprop_main(const float* __restrict__ depth,
                              const float* __restrict__ img,
                              const short* __restrict__ ws_w1,
                              const short* __restrict__ ws_w2,
                              float* __restrict__ out)
{
    __shared__ short s_img[2*IMPLANEP];   // [ch-plane][pix 36x12][8ch] bf16 (13856 B)
    __shared__ short s_h1 [4*H1PLANEP];   // [ch-plane][pix 36x10][8ch] bf16 (23104 B)
    __shared__ float s_depth[340];        // 34x10 replicate-clamped fp32    (1360 B)

    const int tid = threadIdx.x;

    // XCD-contiguous bijective remap: 5120 blocks = 8 XCDs x 640
    int nid = blockIdx.x;
    int oid = (nid & 7)*640 + (nid >> 3);
    int bz = oid / 1280; int rem = oid - bz*1280;
    int by = rem / 20;   int bx = rem - by*20;
    const int gy0 = by*8, gx0 = bx*32;

    const float* imgb = img   + (size_t)bz*16*HW;
    const float* dpb  = depth + (size_t)bz*HW;

    const int lane = tid & 63;
    const int wid  = tid >> 6;

    // ---- stage img tile (36x12 halo, zero at image OOB): one 16B granule/iter ----
    for (int g = tid; g < 864; g += NT) {
        int pixel = g >> 1, half = g & 1;
        int iy = pixel / 36, ix = pixel - iy*36;
        int gy = gy0 + iy - 2, gx = gx0 + ix - 2;
        bool v = ((unsigned)gy < HH) && ((unsigned)gx < WW);
        int cy = min(max(gy, 0), HH-1), cx = min(max(gx, 0), WW-1);
        const float* p = imgb + (size_t)(half*8)*HW + cy*WW + cx;
        float m = v ? 1.f : 0.f;
        short8 vv;
        #pragma unroll
        for (int c = 0; c < 8; ++c) vv[c] = f2bf(m * p[c*HW]);
        *(short8*)&s_img[half*IMPLANEP + pixel*8] = vv;
    }
    if (tid < 340) {
        int ty = tid / 34, tx = tid - ty*34;
        int gy = min(max(gy0 + ty - 1, 0), HH-1);
        int gx = min(max(gx0 + tx - 1, 0), WW-1);
        s_depth[tid] = dpb[gy*WW + gx];
    }
    __syncthreads();

    // ---- conv1 (32x32x16 MFMA, 9 taps + bias tap) -> s_h1 channel-planes ----
    {
        const int oc = lane & 31, cg = lane >> 5;
        short8 a1[10];
        #pragma unroll
        for (int t = 0; t < 10; ++t)
            a1[t] = *(const short8*)&ws_w1[t*512 + oc*16 + cg*8];
        short8 bb = (short8)0;                   // bias-tap B: one-hot 1.0 at k==0
        bb[0] = (cg == 0) ? (short)0x3F80 : (short)0;

        // tap pixel deltas {0,1,2,36,37,38,72,73,74} * 8 shorts (within a plane)
        const int OFS1[9] = {0, 8, 16, 288, 296, 304, 576, 584, 592};
        const int px = lane & 31;

        for (int g = wid; g < 12; g += 8) {      // waves 0-3: 2 groups, 4-7: 1 group
            int hp   = g*32 + px;
            int base = cg*IMPLANEP + hp*8;
            f32x16 acc;
            #pragma unroll
            for (int i = 0; i < 16; ++i) acc[i] = 0.f;
            acc = __builtin_amdgcn_mfma_f32_32x32x16_bf16(a1[9], bb, acc, 0, 0, 0);
            #pragma unroll
            for (int t = 0; t < 9; ++t)
                acc = __builtin_amdgcn_mfma_f32_32x32x16_bf16(
                         a1[t], *(const short8*)&s_img[base + OFS1[t]], acc, 0, 0, 0);

            if (hp < 360) {
                unsigned hy = (unsigned)hp / 36u;
                int hx = hp - (int)hy*36;
                int gy = gy0 + (int)hy - 1, gx = gx0 + hx - 1;
                bool inb = ((unsigned)gy < HH) && ((unsigned)gx < WW);
                #pragma unroll
                for (int q = 0; q < 4; ++q) {      // plane q = channels 8q..8q+7
                    short4v h;
                    #pragma unroll
                    for (int j = 0; j < 4; ++j) {
                        float hv = fmaxf(acc[q*4 + j], 0.f);
                        h[j] = inb ? f2bf(hv) : (short)0;
                    }
                    *(short4v*)&s_h1[q*H1PLANEP + hp*8 + 4*cg] = h;
                }
            }
        }
    }
    __syncthreads();

    // ---- conv2 (16x16x32 MFMA) sliding row-pair + softmax + gather ----
    {
        const int fl = lane & 15, cg2 = lane >> 4;
        short8 a2[9];
        #pragma unroll
        for (int t = 0; t < 9; ++t)
            a2[t] = *(const short8*)&ws_w2[t*512 + fl*32 + cg2*8];

        // wave -> (column half, row pair): 8 waves cover 2 halves x 4 pairs
        const int chh = wid >> 2;            // 0-1
        const int r0  = (wid & 3)*2;         // 0,2,4,6
        const int ox0 = chh*16;
        const int colbase = cg2*H1PLANEP + (ox0 + fl)*8;

        short8 F[4][3];                      // h1 rows r0..r0+3, dx 0..2
        #pragma unroll
        for (int i = 0; i < 4; ++i)
            #pragma unroll
            for (int dx = 0; dx < 3; ++dx)
                F[i][dx] = *(const short8*)&s_h1[colbase + ((r0 + i)*36 + dx)*8];

        f32x4 acc0, acc1;
        #pragma unroll
        for (int i = 0; i < 4; ++i) { acc0[i] = 0.f; acc1[i] = 0.f; }
        #pragma unroll
        for (int i = 0; i < 3; ++i)
            #pragma unroll
            for (int dx = 0; dx < 3; ++dx)
                acc0 = __builtin_amdgcn_mfma_f32_16x16x32_bf16(a2[i*3 + dx], F[i][dx], acc0, 0, 0, 0);
        #pragma unroll
        for (int i = 0; i < 3; ++i)
            #pragma unroll
            for (int dx = 0; dx < 3; ++dx)
                acc1 = __builtin_amdgcn_mfma_f32_16x16x32_bf16(a2[i*3 + dx], F[i + 1][dx], acc1, 0, 0, 0);

        #pragma unroll
        for (int rr = 0; rr < 2; ++rr) {
            f32x4 lg = rr ? acc1 : acc0;
            int oy = r0 + rr, ox = ox0 + fl;
            float num = 0.f, den = 0.f;
            #pragma unroll
            for (int r = 0; r < 4; ++r) {
                int f = cg2*4 + r;               // conv2 output channel
                if (f < 9) {
                    float e = __expf(lg[r]);
                    int fy = f/3, fx = f - fy*3; // tap (dy,dx) = (fy-1, fx-1)
                    float d = s_depth[(oy + fy)*34 + (ox + fx)];
                    den += e; num += e * d;
                }
            }
            num += __shfl_xor(num, 16); den += __shfl_xor(den, 16);
            num += __shfl_xor(num, 32); den += __shfl_xor(den, 32);
            if (cg2 == 0)
                out[(size_t)bz*HW + (size_t)(gy0 + oy)*WW + (gx0 + ox)] = num / den;
        }
    }
}

extern "C" void kernel_launch(void* const* d_in, const int* in_sizes, int n_in,
                              void* d_out, int out_size, void* d_ws, size_t ws_size,
                              hipStream_t stream) {
    const float* depth = (const float*)d_in[0];
    const float* img   = (const float*)d_in[1];
    const float* w1    = (const float*)d_in[2];
    const float* b1    = (const float*)d_in[3];
    const float* gamma = (const float*)d_in[4];
    const float* beta  = (const float*)d_in[5];
    const float* rmean = (const float*)d_in[6];
    const float* rvar  = (const float*)d_in[7];
    const float* w2    = (const float*)d_in[8];
    float* out = (float*)d_out;

    short* ws_w1 = (short*)d_ws;          // 5120 shorts (10 taps x 512)
    short* ws_w2 = ws_w1 + 5120;          // 4608 shorts

    prep_weights<<<16, 256, 0, stream>>>(w1, b1, gamma, beta, rmean, rvar, w2,
                                         ws_w1, ws_w2);
    fastprop_main<<<5120, NT, 0, stream>>>(depth, img, ws_w1, ws_w2, out);
}